// Round 17
// baseline (295.053 us; speedup 1.0000x reference)
//
#include <hip/hip_runtime.h>
#include <hip/hip_bf16.h>
#include <stdint.h>

typedef unsigned short u16;
typedef short bf16x8 __attribute__((ext_vector_type(8)));
typedef u16   u16x8  __attribute__((ext_vector_type(8)));
typedef u16   u16x4  __attribute__((ext_vector_type(4)));
typedef float f32x4  __attribute__((ext_vector_type(4)));

__device__ inline u16 f2bf(float f) {
    uint32_t u = __builtin_bit_cast(uint32_t, f);
    uint32_t r = (u + 0x7FFFu + ((u >> 16) & 1u)) >> 16;
    return (u16)r;
}

__device__ inline void gload16(const void* g, void* l) {
    __builtin_amdgcn_global_load_lds((const __attribute__((address_space(1))) void*)g,
                                     (__attribute__((address_space(3))) void*)l, 16, 0, 0);
}

__device__ inline void pin_barrier() {
    __builtin_amdgcn_sched_barrier(0);
    __builtin_amdgcn_s_barrier();
    __builtin_amdgcn_sched_barrier(0);
}

#define MFMA16(a, b, c) __builtin_amdgcn_mfma_f32_16x16x32_bf16((a), (b), (c), 0, 0, 0)

// -------- prep: gather-cast xe AND both weight transposes, one launch -------
// blocks 0..8191: xe rows; 8192..10495: Wqkv tiles; 10496..11263: Wo tiles
__global__ __launch_bounds__(256) void k_prep_all(
    const float* __restrict__ x, u16* __restrict__ xe,
    const float* __restrict__ Wqkv, u16* __restrict__ WQKVT,
    const float* __restrict__ Wo, u16* __restrict__ WOT) {
    const int bid = blockIdx.x, tid = threadIdx.x;
    if (bid < 8192) {
        int b = bid >> 12, tt = bid & 4095;
        const float* src = x + ((size_t)b * 8192 + 2 * (size_t)tt) * 1024;
        float4 v = ((const float4*)src)[tid];
        u16x4 o = { f2bf(v.x), f2bf(v.y), f2bf(v.z), f2bf(v.w) };
        *(u16x4*)(xe + (size_t)bid * 1024 + tid * 4) = o;
        return;
    }
    int t = bid - 8192;
    const float* s; u16* dst;
    int k0, e0, srcCols, dstStride, rowBase, colBase;
    if (t < 2304) {
        int layer = t / 768, r = t % 768;
        int kx = r % 16, ey = r / 16;          // 16 x 48
        k0 = kx * 64; e0 = ey * 64;
        s = Wqkv + (size_t)layer * 1024 * 3072;
        dst = WQKVT; srcCols = 3072; dstStride = 1024;
        rowBase = layer * 3072 + e0; colBase = k0;
    } else {
        int u = t - 2304;
        int layer = u / 256, r = u % 256;
        int kx = r % 16, ey = r / 16;          // 16 x 16
        k0 = kx * 64; e0 = ey * 64;
        s = Wo + (size_t)layer * 1024 * 1024;
        dst = WOT; srcCols = 1024; dstStride = 3072;
        rowBase = e0; colBase = layer * 1024 + k0;
    }
    __shared__ u16 T[64][66];
#pragma unroll
    for (int p = 0; p < 16; ++p) {
        int l = p * 256 + tid;
        int kl = l >> 6, el = l & 63;
        T[kl][el] = f2bf(s[(size_t)(k0 + kl) * srcCols + e0 + el]);
    }
    __syncthreads();
#pragma unroll
    for (int p = 0; p < 16; ++p) {
        int l = p * 256 + tid;
        int eo = l >> 6, ko = l & 63;
        dst[(size_t)(rowBase + eo) * dstStride + colBase + ko] = T[ko][eo];
    }
}

// ====== 256x256 BK=64 GEMM (R6 structure) with A-resident XCD mapping =======
// R17: all stage-issues hoisted to the top of the tile body (max flight time;
// same vmcnt ledger — stages write the other buffer, no hazard).
template <int BN, bool BF16OUT>
__global__ __launch_bounds__(512, 2) void k_gemm4(
    const u16* __restrict__ A, const u16* __restrict__ B, void* __restrict__ C,
    const float* __restrict__ bias0, const float* __restrict__ bias1,
    const float* __restrict__ bias2, int K, int lda, int ldb, int ldc,
    int gxl) {
    constexpr int WN = BN / 64;
    constexpr int WM = 8 / WN;
    constexpr int MFRAG = 256 / (WM * 16);
    constexpr int NB = BN / 64;
    constexpr int BUFSZ = 32768 + BN * 128;

    __shared__ __align__(16) char smem[131072];
    const int tid = threadIdx.x, lane = tid & 63, wave = tid >> 6;
    const int wr = wave / WN, wc = wave % WN;

    // A-resident XCD mapping: bx = xcd*gxl + idx%gxl, by = idx/gxl (bijective)
    const int bid = blockIdx.x;
    const int xcd = bid & 7, idx = bid >> 3;
    const int bx = xcd * gxl + (idx % gxl);
    const int by = idx / gxl;
    const int row0 = bx << 8, col0 = by * BN;

    const size_t lda2 = (size_t)lda * 2, ldb2 = (size_t)ldb * 2;
    const char* pA0 = (const char*)A +
        (size_t)(row0 + wave * 8 + (lane >> 3)) * lda2 + ((lane & 7) ^ (lane >> 3)) * 16;
    const char* pB0 = (const char*)B +
        (size_t)(col0 + wave * 8 + (lane >> 3)) * ldb2 + ((lane & 7) ^ (lane >> 3)) * 16;

#define STA(i, sb, kof) gload16(pA0 + (size_t)(i) * 64 * lda2 + (kof), (sb) + ((i) * 8 + wave) * 1024)
#define STB(i, sb, kof) gload16(pB0 + (size_t)(i) * 64 * ldb2 + (kof), (sb) + 32768 + ((i) * 8 + wave) * 1024)

    const int la = lane & 15, lg = lane >> 4, l7 = lane & 7;
    const int offK0 = la * 128 + ((lg ^ l7) << 4);
    const int offK1 = la * 128 + (((4 + lg) ^ l7) << 4);

    f32x4 acc[MFRAG][4] = {};
    const int nt = K >> 6;

    char* const BUF0 = smem;
    char* const BUF1 = smem + BUFSZ;

    {
#pragma unroll
        for (int i = 0; i < 4; ++i) STA(i, BUF0, 0);
#pragma unroll
        for (int i = 0; i < NB; ++i) STB(i, BUF0, 0);
        __builtin_amdgcn_sched_barrier(0);
        asm volatile("s_waitcnt vmcnt(0)" ::: "memory");
        pin_barrier();
    }

    for (int t = 0; t < nt; ++t) {
        char* rq = (t & 1) ? BUF1 : BUF0;
        char* sq = (t & 1) ? BUF0 : BUF1;
        const bool st = (t + 1 < nt);
        const size_t kof = (size_t)(t + 1) * 128;
        const char* aB = rq + wr * (MFRAG * 2048);
        const char* bB = rq + 32768 + wc * 8192;

        // ---- all stage issues first: max issue-to-drain flight time ----
        if (st) {
            STA(0, sq, kof); STA(1, sq, kof); STA(2, sq, kof); STA(3, sq, kof);
#pragma unroll
            for (int i = 0; i < NB; ++i) STB(i, sq, kof);
        }
        bf16x8 af[4], ag[4], b0[4], b1[4];
#pragma unroll
        for (int n = 0; n < 4; ++n) b0[n] = *(const bf16x8*)(bB + n * 2048 + offK0);
#pragma unroll
        for (int m = 0; m < 4; ++m) af[m] = *(const bf16x8*)(aB + m * 2048 + offK0);
#pragma unroll
        for (int m = 0; m < 4; ++m)
            ag[m] = *(const bf16x8*)(aB + 8192 + m * 2048 + offK0);
#pragma unroll
        for (int n = 0; n < 4; ++n) b1[n] = *(const bf16x8*)(bB + n * 2048 + offK1);
        __builtin_amdgcn_s_setprio(1);
#pragma unroll
        for (int m = 0; m < 4; ++m)
#pragma unroll
            for (int n = 0; n < 4; ++n)
                acc[m][n] = MFMA16(af[m], b0[n], acc[m][n]);
        __builtin_amdgcn_s_setprio(0);
        __builtin_amdgcn_sched_barrier(0);
#pragma unroll
        for (int m = 0; m < 4; ++m) af[m] = *(const bf16x8*)(aB + m * 2048 + offK1);
        __builtin_amdgcn_s_setprio(1);
#pragma unroll
        for (int m = 0; m < 4; ++m)
#pragma unroll
            for (int n = 0; n < 4; ++n)
                acc[4 + m][n] = MFMA16(ag[m], b0[n], acc[4 + m][n]);
        __builtin_amdgcn_s_setprio(0);
        __builtin_amdgcn_sched_barrier(0);
#pragma unroll
        for (int m = 0; m < 4; ++m)
            ag[m] = *(const bf16x8*)(aB + 8192 + m * 2048 + offK1);
        __builtin_amdgcn_s_setprio(1);
#pragma unroll
        for (int m = 0; m < 4; ++m)
#pragma unroll
            for (int n = 0; n < 4; ++n)
                acc[m][n] = MFMA16(af[m], b1[n], acc[m][n]);
        __builtin_amdgcn_s_setprio(0);
        __builtin_amdgcn_sched_barrier(0);
        __builtin_amdgcn_s_setprio(1);
#pragma unroll
        for (int m = 0; m < 4; ++m)
#pragma unroll
            for (int n = 0; n < 4; ++n)
                acc[4 + m][n] = MFMA16(ag[m], b1[n], acc[4 + m][n]);
        __builtin_amdgcn_s_setprio(0);
        __builtin_amdgcn_sched_barrier(0);
        asm volatile("s_waitcnt vmcnt(0)" ::: "memory");
        pin_barrier();
    }
#undef STA
#undef STB

    {
        char* cst = smem;
        const int g4 = (lane >> 4) << 2, cl = lane & 15;
#pragma unroll
        for (int n = 0; n < 4; ++n) {
            int col = wc * 64 + n * 16 + cl;
            float bs = bias0[col0 + col];
            if (bias1) bs += bias1[col0 + col];
            if (bias2) bs += bias2[col0 + col];
#pragma unroll
            for (int m = 0; m < MFRAG; ++m) {
#pragma unroll
                for (int r = 0; r < 4; ++r) {
                    int row = wr * (MFRAG * 16) + m * 16 + g4 + r;
                    float v = acc[m][n][r] + bs;
                    if (BF16OUT) {
                        int scol = col ^ (((row >> 2) & 3) << 3);
                        *(u16*)(cst + row * 512 + scol * 2) = f2bf(v);
                    } else {
                        int scol = col ^ (((row >> 2) & 3) << 2);
                        *(float*)(cst + row * 512 + scol * 4) = v;
                    }
                }
            }
        }
        pin_barrier();
        const int esz = BF16OUT ? 2 : 4;
#pragma unroll
        for (int it = 0; it < 16; ++it) {
            int id = it * 512 + tid;
            int row = id >> 5, c16 = id & 31;
            int sc16 = c16 ^ ((row >> 2) & 3);
            u16x8 v = *(const u16x8*)(cst + row * 512 + sc16 * 16);
            char* dst = (char*)C + ((size_t)(row0 + row) * ldc + col0) * esz + c16 * 16;
            *(u16x8*)dst = v;
        }
    }
}

// ====== 128x128 BK=64 GEMM, 4 waves, 2 blocks/CU (output projection) ========
// A-resident XCD mapping [R16 verified]; stage issues hoisted (R17).
__global__ __launch_bounds__(256, 2) void k_gemm4b(
    const u16* __restrict__ A, const u16* __restrict__ B, float* __restrict__ C,
    const float* __restrict__ bias0, const float* __restrict__ bias1,
    const float* __restrict__ bias2, int K, int lda, int ldb, int ldc,
    int gxl) {
    __shared__ __align__(16) char smem[65536];
    const int tid = threadIdx.x, lane = tid & 63, wave = tid >> 6;
    const int wr = wave >> 1, wc = wave & 1;   // 2M x 2N

    const int bid = blockIdx.x;
    const int xcd = bid & 7, idx = bid >> 3;
    const int bx = xcd * gxl + (idx % gxl);
    const int by = idx / gxl;
    const int row0 = bx << 7, col0 = by << 7;

    const size_t lda2 = (size_t)lda * 2, ldb2 = (size_t)ldb * 2;
    const int sRow = tid >> 3;
    const int sChunk = (tid & 7) ^ (sRow & 7);
    const char* pA0 = (const char*)A + (size_t)(row0 + sRow) * lda2 + sChunk * 16;
    const char* pB0 = (const char*)B + (size_t)(col0 + sRow) * ldb2 + sChunk * 16;

#define STA_(i, sb, kof) gload16(pA0 + (size_t)(i) * 32 * lda2 + (kof), \
                                 (sb) + (i) * 4096 + wave * 1024)
#define STB_(i, sb, kof) gload16(pB0 + (size_t)(i) * 32 * ldb2 + (kof), \
                                 (sb) + 16384 + (i) * 4096 + wave * 1024)

    const int la = lane & 15, lg = lane >> 4;
    const int loff0 = la * 128 + (((lg) ^ (la & 7)) << 4);
    const int loff1 = la * 128 + (((4 + lg) ^ (la & 7)) << 4);

    f32x4 acc[4][4] = {};
    const int nt = K >> 6;

#pragma unroll
    for (int i = 0; i < 4; ++i) STA_(i, smem, 0);
#pragma unroll
    for (int i = 0; i < 4; ++i) STB_(i, smem, 0);
    __builtin_amdgcn_sched_barrier(0);
    asm volatile("s_waitcnt vmcnt(0)" ::: "memory");
    pin_barrier();

    for (int t = 0; t < nt; ++t) {
        char* rq = smem + (t & 1) * 32768;
        char* sq = smem + ((t & 1) ^ 1) * 32768;
        const bool st = (t + 1 < nt);
        const size_t kof = (size_t)(t + 1) * 128;
        const char* aB = rq + wr * 8192;
        const char* bB = rq + 16384 + wc * 8192;

        // ---- all stage issues first ----
        if (st) {
            STA_(0, sq, kof); STA_(1, sq, kof); STA_(2, sq, kof); STA_(3, sq, kof);
            STB_(0, sq, kof); STB_(1, sq, kof); STB_(2, sq, kof); STB_(3, sq, kof);
        }
        bf16x8 a0[4], a1[4], b0f[4], b1f[4];
#pragma unroll
        for (int n = 0; n < 4; ++n) b0f[n] = *(const bf16x8*)(bB + n * 2048 + loff0);
#pragma unroll
        for (int m = 0; m < 4; ++m) a0[m] = *(const bf16x8*)(aB + m * 2048 + loff0);
#pragma unroll
        for (int n = 0; n < 4; ++n) b1f[n] = *(const bf16x8*)(bB + n * 2048 + loff1);
#pragma unroll
        for (int m = 0; m < 4; ++m) a1[m] = *(const bf16x8*)(aB + m * 2048 + loff1);

        __builtin_amdgcn_sched_barrier(0);
        __builtin_amdgcn_s_setprio(1);
#pragma unroll
        for (int m = 0; m < 4; ++m)
#pragma unroll
            for (int n = 0; n < 4; ++n)
                acc[m][n] = MFMA16(a0[m], b0f[n], acc[m][n]);
        __builtin_amdgcn_s_setprio(0);
        __builtin_amdgcn_sched_barrier(0);
        __builtin_amdgcn_s_setprio(1);
#pragma unroll
        for (int m = 0; m < 4; ++m)
#pragma unroll
            for (int n = 0; n < 4; ++n)
                acc[m][n] = MFMA16(a1[m], b1f[n], acc[m][n]);
        __builtin_amdgcn_s_setprio(0);
        __builtin_amdgcn_sched_barrier(0);
        asm volatile("s_waitcnt vmcnt(0)" ::: "memory");
        pin_barrier();
    }
#undef STA_
#undef STB_

    {
        float* cst = (float*)smem;
        const int g4 = lg << 2;
#pragma unroll
        for (int n = 0; n < 4; ++n) {
            int col = wc * 64 + n * 16 + la;
            float bs = bias0[col0 + col] + bias1[col0 + col] + bias2[col0 + col];
#pragma unroll
            for (int m = 0; m < 4; ++m) {
#pragma unroll
                for (int r = 0; r < 4; ++r) {
                    int row = wr * 64 + m * 16 + g4 + r;
                    int scol = col ^ (((row >> 2) & 3) << 3);
                    cst[row * 128 + scol] = acc[m][n][r] + bs;
                }
            }
        }
        pin_barrier();
#pragma unroll
        for (int it = 0; it < 16; ++it) {
            int id = it * 256 + tid;       // 16B chunk: row*32 + c16
            int row = id >> 5, c16 = id & 31;
            int sc16 = c16 ^ (((row >> 2) & 3) << 1);
            u16x8 v = *(const u16x8*)((char*)cst + row * 512 + sc16 * 16);
            *(u16x8*)((char*)C + ((size_t)(row0 + row) * ldc + col0) * 4 + c16 * 16) = v;
        }
    }
}

// ---------------- attention: HP heads per block + XCD-chunked swizzle -------
template <int S, int HP>
__global__ __launch_bounds__(256) void k_attn(const u16* __restrict__ qkv,
                                              u16* __restrict__ ab, int layer) {
    constexpr int NCT = S / 16;
    constexpr int RPW = (S == 32) ? 1 : S / 64;
    constexpr int ACTIVE = (S == 32) ? 2 : 4;
    constexpr int KST = S / 32;
    constexpr int VSTRIDE = 2 * S;
    constexpr int VMASK = VSTRIDE / 16 - 1;
    constexpr int HPB = 16 / HP;               // head-groups per (b,n)

    __shared__ __align__(16) char KS[HP][S * 128];
    __shared__ __align__(16) char VTS[HP][64 * VSTRIDE];
    __shared__ __align__(16) char PS[HP][S * VSTRIDE];

    const int nwg = gridDim.x, bid = blockIdx.x;
    const int cpx = nwg >> 3;
    const int swz = (bid & 7) * cpx + (bid >> 3);

    const int per_b = (4096 / S) * HPB;
    const int b = swz / per_b;
    const int r0 = swz % per_b;
    const int n = r0 / HPB, hbase = (r0 % HPB) * HP;
    const int token0 = b * 4096 + n * S;
    const int tid = threadIdx.x, lane = tid & 63, wave = tid >> 6;
    const int hp = (HP == 2) ? (wave >> 1) : 0;         // this wave's head
    const int lw = (HP == 2) ? (wave & 1) : wave;       // local wave in head

    constexpr int CHUNKS = S / 32;
#pragma unroll
    for (int hs = 0; hs < HP; ++hs) {
        const int colQ = layer * 3072 + (hbase + hs) * 64;
#pragma unroll
        for (int c = 0; c < CHUNKS; ++c) {
            int lc = c * 256 + tid;
            int row = lc >> 3, off = (lc & 7) * 16;
            const char* base = (const char*)qkv + ((size_t)(token0 + row) * 9216 + colQ) * 2 + off;
            u16x8 kv = *(const u16x8*)(base + 1024 * 2);
            *(u16x8*)(KS[hs] + row * 128 + (off ^ ((row & 7) << 4))) = kv;
            u16x8 vv = *(const u16x8*)(base + 2048 * 2);
            int cb = off >> 1;
#pragma unroll
            for (int e = 0; e < 8; ++e) {
                int col = cb + e;
                *(u16*)(VTS[hs] + col * VSTRIDE + ((row * 2) ^ ((col & VMASK) << 4))) = vv[e];
            }
        }
    }
    __syncthreads();

    const int colQ = layer * 3072 + (hbase + hp) * 64;
    f32x4 sacc[RPW][NCT] = {};
    if (lw < ACTIVE) {
#pragma unroll
        for (int rl = 0; rl < RPW; ++rl) {
            int rt = lw * RPW + rl;
#pragma unroll
            for (int ks2 = 0; ks2 < 2; ++ks2) {
                int qrow = token0 + rt * 16 + (lane & 15);
                int kbyte = ks2 * 64 + ((lane >> 4) << 4);
                bf16x8 aq = *(const bf16x8*)((const char*)qkv +
                              ((size_t)qrow * 9216 + colQ) * 2 + kbyte);
#pragma unroll
                for (int ct = 0; ct < NCT; ++ct) {
                    int krow = ct * 16 + (lane & 15);
                    bf16x8 bk = *(const bf16x8*)(KS[hp] + krow * 128 + (kbyte ^ ((krow & 7) << 4)));
                    sacc[rl][ct] = MFMA16(aq, bk, sacc[rl][ct]);
                }
            }
        }
#pragma unroll
        for (int rl = 0; rl < RPW; ++rl) {
            int rt = lw * RPW + rl;
#pragma unroll
            for (int r = 0; r < 4; ++r) {
                float vals[NCT];
                float m = -1e30f;
#pragma unroll
                for (int ct = 0; ct < NCT; ++ct) {
                    vals[ct] = sacc[rl][ct][r] * 0.125f;
                    m = fmaxf(m, vals[ct]);
                }
#pragma unroll
                for (int d = 1; d < 16; d <<= 1) m = fmaxf(m, __shfl_xor(m, d, 64));
                float sum = 0.f;
#pragma unroll
                for (int ct = 0; ct < NCT; ++ct) {
                    float p = exp2f((vals[ct] - m) * 1.44269504f);
                    vals[ct] = p;
                    sum += p;
                }
#pragma unroll
                for (int d = 1; d < 16; d <<= 1) sum += __shfl_xor(sum, d, 64);
                float inv = 1.0f / sum;
                int row = rt * 16 + ((lane >> 4) << 2) + r;
#pragma unroll
                for (int ct = 0; ct < NCT; ++ct) {
                    int col = ct * 16 + (lane & 15);
                    *(u16*)(PS[hp] + row * VSTRIDE + ((col * 2) ^ ((row & VMASK) << 4))) =
                        f2bf(vals[ct] * inv);
                }
            }
        }
    }
    __syncthreads();

    if (lw < ACTIVE) {
        const int colA = layer * 1024 + (hbase + hp) * 64;
#pragma unroll
        for (int rl = 0; rl < RPW; ++rl) {
            int rt = lw * RPW + rl;
            f32x4 oacc[4] = {};
#pragma unroll
            for (int ks2 = 0; ks2 < KST; ++ks2) {
                int kbyte = ks2 * 64 + ((lane >> 4) << 4);
                int prow = rt * 16 + (lane & 15);
                bf16x8 ap = *(const bf16x8*)(PS[hp] + prow * VSTRIDE + (kbyte ^ ((prow & VMASK) << 4)));
#pragma unroll
                for (int ct = 0; ct < 4; ++ct) {
                    int vcol = ct * 16 + (lane & 15);
                    bf16x8 bv = *(const bf16x8*)(VTS[hp] + vcol * VSTRIDE + (kbyte ^ ((vcol & VMASK) << 4)));
                    oacc[ct] = MFMA16(ap, bv, oacc[ct]);
                }
            }
#pragma unroll
            for (int ct = 0; ct < 4; ++ct) {
#pragma unroll
                for (int r = 0; r < 4; ++r) {
                    int row = token0 + rt * 16 + ((lane >> 4) << 2) + r;
                    int col = colA + ct * 16 + (lane & 15);
                    ab[(size_t)row * 3072 + col] = f2bf(oacc[ct][r]);
                }
            }
        }
    }
}

// ---------------------------------------------------------------------------
extern "C" void kernel_launch(void* const* d_in, const int* in_sizes, int n_in,
                              void* d_out, int out_size, void* d_ws, size_t ws_size,
                              hipStream_t stream) {
    const float* x    = (const float*)d_in[0];
    const float* Wqkv = (const float*)d_in[1];
    const float* bqkv = (const float*)d_in[2];
    const float* Wo   = (const float*)d_in[3];
    const float* bo   = (const float*)d_in[4];

    char* ws = (char*)d_ws;
    u16* XE    = (u16*)(ws);                       // [8192][1024]
    u16* WQKVT = (u16*)(ws + 16777216);            // [9216][1024]
    u16* WOT   = (u16*)(ws + 35651584);            // [1024][3072]
    u16* QKVB  = (u16*)(ws + 41943040);            // [8192][9216]
    u16* ABUF  = (u16*)(ws + 192937984);           // [8192][3072]

    // all prep in one launch: xe gather-cast + both weight transposes
    k_prep_all<<<11264, 256, 0, stream>>>(x, XE, Wqkv, WQKVT, Wo, WOT);

    // QKV projection for all 3 layers: [8192,1024] @ [1024,9216]
    // grid 1152 = 8 XCD x (4 bx x 36 by); gxl = 4
    k_gemm4<256, true><<<dim3(1152), 512, 0, stream>>>(
        XE, WQKVT, QKVB, bqkv, nullptr, nullptr, 1024, 1024, 1024, 9216, 4);

    // dilated segment attention per layer (S=32 packs 2 heads/block)
    k_attn<32, 2><<<2048, 256, 0, stream>>>(QKVB, ABUF, 0);
    k_attn<64, 1><<<2048, 256, 0, stream>>>(QKVB, ABUF, 1);
    k_attn<128, 1><<<1024, 256, 0, stream>>>(QKVB, ABUF, 2);

    // fused output projection + layer sum: [8192,3072] @ [3072,1024]
    // grid 512 = 8 XCD x (8 bx x 8 by); gxl = 8 (A-resident mapping)
    k_gemm4b<<<dim3(512), 256, 0, stream>>>(
        ABUF, WOT, (float*)d_out, bo, bo + 1024, bo + 2048,
        3072, 3072, 3072, 1024, 8);
}

// Round 18
// 293.955 us; speedup vs baseline: 1.0037x; 1.0037x over previous
//
#include <hip/hip_runtime.h>
#include <hip/hip_bf16.h>
#include <stdint.h>

typedef unsigned short u16;
typedef short bf16x8 __attribute__((ext_vector_type(8)));
typedef u16   u16x8  __attribute__((ext_vector_type(8)));
typedef u16   u16x4  __attribute__((ext_vector_type(4)));
typedef float f32x4  __attribute__((ext_vector_type(4)));

__device__ inline u16 f2bf(float f) {
    uint32_t u = __builtin_bit_cast(uint32_t, f);
    uint32_t r = (u + 0x7FFFu + ((u >> 16) & 1u)) >> 16;
    return (u16)r;
}

__device__ inline void gload16(const void* g, void* l) {
    __builtin_amdgcn_global_load_lds((const __attribute__((address_space(1))) void*)g,
                                     (__attribute__((address_space(3))) void*)l, 16, 0, 0);
}

__device__ inline void pin_barrier() {
    __builtin_amdgcn_sched_barrier(0);
    __builtin_amdgcn_s_barrier();
    __builtin_amdgcn_sched_barrier(0);
}

#define MFMA16(a, b, c) __builtin_amdgcn_mfma_f32_16x16x32_bf16((a), (b), (c), 0, 0, 0)

// ---------------- prep: gather even rows of x, cast to bf16 -----------------
__global__ __launch_bounds__(256) void k_prep_xe(const float* __restrict__ x,
                                                 u16* __restrict__ xe) {
    int row = blockIdx.x;              // 0..8191
    int b = row >> 12, tt = row & 4095;
    const float* src = x + ((size_t)b * 8192 + 2 * (size_t)tt) * 1024;
    float4 v = ((const float4*)src)[threadIdx.x];
    u16x4 o = { f2bf(v.x), f2bf(v.y), f2bf(v.z), f2bf(v.w) };
    *(u16x4*)(xe + (size_t)row * 1024 + threadIdx.x * 4) = o;
}

// ------- prep: BOTH weight transposes in one launch (1D-flattened) ----------
__global__ __launch_bounds__(256) void k_transpose_both(
    const float* __restrict__ Wqkv, u16* __restrict__ WQKVT,
    const float* __restrict__ Wo, u16* __restrict__ WOT) {
    int t = blockIdx.x;
    const float* s; u16* dst;
    int k0, e0, srcCols, dstStride, rowBase, colBase;
    if (t < 2304) {
        int layer = t / 768, r = t % 768;
        int kx = r % 16, ey = r / 16;          // 16 x 48
        k0 = kx * 64; e0 = ey * 64;
        s = Wqkv + (size_t)layer * 1024 * 3072;
        dst = WQKVT; srcCols = 3072; dstStride = 1024;
        rowBase = layer * 3072 + e0; colBase = k0;
    } else {
        int u = t - 2304;
        int layer = u / 256, r = u % 256;
        int kx = r % 16, ey = r / 16;          // 16 x 16
        k0 = kx * 64; e0 = ey * 64;
        s = Wo + (size_t)layer * 1024 * 1024;
        dst = WOT; srcCols = 1024; dstStride = 3072;
        rowBase = e0; colBase = layer * 1024 + k0;
    }
    __shared__ u16 T[64][66];
    int tid = threadIdx.x;
#pragma unroll
    for (int p = 0; p < 16; ++p) {
        int l = p * 256 + tid;
        int kl = l >> 6, el = l & 63;
        T[kl][el] = f2bf(s[(size_t)(k0 + kl) * srcCols + e0 + el]);
    }
    __syncthreads();
#pragma unroll
    for (int p = 0; p < 16; ++p) {
        int l = p * 256 + tid;
        int eo = l >> 6, ko = l & 63;
        dst[(size_t)(rowBase + eo) * dstStride + colBase + ko] = T[ko][eo];
    }
}

// ====== 256x256 BK=64 GEMM (R6 structure) with A-resident XCD mapping =======
// Each XCD owns a fixed 4-wide bx strip (bx = xcd*4 + idx%4, by = idx/4):
// the XCD's 4 A-panels (2MB) stay L2-resident for the whole kernel.
// [R15/R16 verified: FETCH 309->115MB, dur 172->164us; R17 stage-hoist
// regressed (ds_read->MFMA critical path) -> R6 interleaved placement kept]
template <int BN, bool BF16OUT>
__global__ __launch_bounds__(512, 2) void k_gemm4(
    const u16* __restrict__ A, const u16* __restrict__ B, void* __restrict__ C,
    const float* __restrict__ bias0, const float* __restrict__ bias1,
    const float* __restrict__ bias2, int K, int lda, int ldb, int ldc,
    int gxl) {
    constexpr int WN = BN / 64;
    constexpr int WM = 8 / WN;
    constexpr int MFRAG = 256 / (WM * 16);
    constexpr int NB = BN / 64;
    constexpr int BUFSZ = 32768 + BN * 128;

    __shared__ __align__(16) char smem[131072];
    const int tid = threadIdx.x, lane = tid & 63, wave = tid >> 6;
    const int wr = wave / WN, wc = wave % WN;

    // A-resident XCD mapping: bx = xcd*gxl + idx%gxl, by = idx/gxl (bijective)
    const int bid = blockIdx.x;
    const int xcd = bid & 7, idx = bid >> 3;
    const int bx = xcd * gxl + (idx % gxl);
    const int by = idx / gxl;
    const int row0 = bx << 8, col0 = by * BN;

    const size_t lda2 = (size_t)lda * 2, ldb2 = (size_t)ldb * 2;
    const char* pA0 = (const char*)A +
        (size_t)(row0 + wave * 8 + (lane >> 3)) * lda2 + ((lane & 7) ^ (lane >> 3)) * 16;
    const char* pB0 = (const char*)B +
        (size_t)(col0 + wave * 8 + (lane >> 3)) * ldb2 + ((lane & 7) ^ (lane >> 3)) * 16;

#define STA(i, sb, kof) gload16(pA0 + (size_t)(i) * 64 * lda2 + (kof), (sb) + ((i) * 8 + wave) * 1024)
#define STB(i, sb, kof) gload16(pB0 + (size_t)(i) * 64 * ldb2 + (kof), (sb) + 32768 + ((i) * 8 + wave) * 1024)

    const int la = lane & 15, lg = lane >> 4, l7 = lane & 7;
    const int offK0 = la * 128 + ((lg ^ l7) << 4);
    const int offK1 = la * 128 + (((4 + lg) ^ l7) << 4);

    f32x4 acc[MFRAG][4] = {};
    const int nt = K >> 6;

    char* const BUF0 = smem;
    char* const BUF1 = smem + BUFSZ;

    {
#pragma unroll
        for (int i = 0; i < 4; ++i) STA(i, BUF0, 0);
#pragma unroll
        for (int i = 0; i < NB; ++i) STB(i, BUF0, 0);
        __builtin_amdgcn_sched_barrier(0);
        asm volatile("s_waitcnt vmcnt(0)" ::: "memory");
        pin_barrier();
    }

    for (int t = 0; t < nt; ++t) {
        char* rq = (t & 1) ? BUF1 : BUF0;
        char* sq = (t & 1) ? BUF0 : BUF1;
        const bool st = (t + 1 < nt);
        const size_t kof = (size_t)(t + 1) * 128;
        const char* aB = rq + wr * (MFRAG * 2048);
        const char* bB = rq + 32768 + wc * 8192;

        bf16x8 af[4], ag[4], b0[4], b1[4];
#pragma unroll
        for (int n = 0; n < 4; ++n) b0[n] = *(const bf16x8*)(bB + n * 2048 + offK0);
#pragma unroll
        for (int m = 0; m < 4; ++m) af[m] = *(const bf16x8*)(aB + m * 2048 + offK0);
        if (st) { STA(0, sq, kof); STA(1, sq, kof); }
#pragma unroll
        for (int m = 0; m < 4; ++m)
            ag[m] = *(const bf16x8*)(aB + 8192 + m * 2048 + offK0);
#pragma unroll
        for (int n = 0; n < 4; ++n) b1[n] = *(const bf16x8*)(bB + n * 2048 + offK1);
        if (st) {
            STA(2, sq, kof); STA(3, sq, kof);
#pragma unroll
            for (int i = 0; i < NB; ++i) STB(i, sq, kof);
        }
        __builtin_amdgcn_s_setprio(1);
#pragma unroll
        for (int m = 0; m < 4; ++m)
#pragma unroll
            for (int n = 0; n < 4; ++n)
                acc[m][n] = MFMA16(af[m], b0[n], acc[m][n]);
        __builtin_amdgcn_s_setprio(0);
        __builtin_amdgcn_sched_barrier(0);
#pragma unroll
        for (int m = 0; m < 4; ++m) af[m] = *(const bf16x8*)(aB + m * 2048 + offK1);
        __builtin_amdgcn_s_setprio(1);
#pragma unroll
        for (int m = 0; m < 4; ++m)
#pragma unroll
            for (int n = 0; n < 4; ++n)
                acc[4 + m][n] = MFMA16(ag[m], b0[n], acc[4 + m][n]);
        __builtin_amdgcn_s_setprio(0);
        __builtin_amdgcn_sched_barrier(0);
#pragma unroll
        for (int m = 0; m < 4; ++m)
            ag[m] = *(const bf16x8*)(aB + 8192 + m * 2048 + offK1);
        __builtin_amdgcn_s_setprio(1);
#pragma unroll
        for (int m = 0; m < 4; ++m)
#pragma unroll
            for (int n = 0; n < 4; ++n)
                acc[m][n] = MFMA16(af[m], b1[n], acc[m][n]);
        __builtin_amdgcn_s_setprio(0);
        __builtin_amdgcn_sched_barrier(0);
        __builtin_amdgcn_s_setprio(1);
#pragma unroll
        for (int m = 0; m < 4; ++m)
#pragma unroll
            for (int n = 0; n < 4; ++n)
                acc[4 + m][n] = MFMA16(ag[m], b1[n], acc[4 + m][n]);
        __builtin_amdgcn_s_setprio(0);
        __builtin_amdgcn_sched_barrier(0);
        asm volatile("s_waitcnt vmcnt(0)" ::: "memory");
        pin_barrier();
    }
#undef STA
#undef STB

    {
        char* cst = smem;
        const int g4 = (lane >> 4) << 2, cl = lane & 15;
#pragma unroll
        for (int n = 0; n < 4; ++n) {
            int col = wc * 64 + n * 16 + cl;
            float bs = bias0[col0 + col];
            if (bias1) bs += bias1[col0 + col];
            if (bias2) bs += bias2[col0 + col];
#pragma unroll
            for (int m = 0; m < MFRAG; ++m) {
#pragma unroll
                for (int r = 0; r < 4; ++r) {
                    int row = wr * (MFRAG * 16) + m * 16 + g4 + r;
                    float v = acc[m][n][r] + bs;
                    if (BF16OUT) {
                        int scol = col ^ (((row >> 2) & 3) << 3);
                        *(u16*)(cst + row * 512 + scol * 2) = f2bf(v);
                    } else {
                        int scol = col ^ (((row >> 2) & 3) << 2);
                        *(float*)(cst + row * 512 + scol * 4) = v;
                    }
                }
            }
        }
        pin_barrier();
        const int esz = BF16OUT ? 2 : 4;
#pragma unroll
        for (int it = 0; it < 16; ++it) {
            int id = it * 512 + tid;
            int row = id >> 5, c16 = id & 31;
            int sc16 = c16 ^ ((row >> 2) & 3);
            u16x8 v = *(const u16x8*)(cst + row * 512 + sc16 * 16);
            char* dst = (char*)C + ((size_t)(row0 + row) * ldc + col0) * esz + c16 * 16;
            *(u16x8*)dst = v;
        }
    }
}

// ====== 128x128 BK=64 GEMM, 4 waves, 2 blocks/CU (output projection) ========
// A-resident XCD mapping (bx = xcd*8 + idx%8, by = idx/8) [R16 verified].
__global__ __launch_bounds__(256, 2) void k_gemm4b(
    const u16* __restrict__ A, const u16* __restrict__ B, float* __restrict__ C,
    const float* __restrict__ bias0, const float* __restrict__ bias1,
    const float* __restrict__ bias2, int K, int lda, int ldb, int ldc,
    int gxl) {
    __shared__ __align__(16) char smem[65536];
    const int tid = threadIdx.x, lane = tid & 63, wave = tid >> 6;
    const int wr = wave >> 1, wc = wave & 1;   // 2M x 2N

    const int bid = blockIdx.x;
    const int xcd = bid & 7, idx = bid >> 3;
    const int bx = xcd * gxl + (idx % gxl);
    const int by = idx / gxl;
    const int row0 = bx << 7, col0 = by << 7;

    const size_t lda2 = (size_t)lda * 2, ldb2 = (size_t)ldb * 2;
    const int sRow = tid >> 3;
    const int sChunk = (tid & 7) ^ (sRow & 7);
    const char* pA0 = (const char*)A + (size_t)(row0 + sRow) * lda2 + sChunk * 16;
    const char* pB0 = (const char*)B + (size_t)(col0 + sRow) * ldb2 + sChunk * 16;

#define STA_(i, sb, kof) gload16(pA0 + (size_t)(i) * 32 * lda2 + (kof), \
                                 (sb) + (i) * 4096 + wave * 1024)
#define STB_(i, sb, kof) gload16(pB0 + (size_t)(i) * 32 * ldb2 + (kof), \
                                 (sb) + 16384 + (i) * 4096 + wave * 1024)

    const int la = lane & 15, lg = lane >> 4;
    const int loff0 = la * 128 + (((lg) ^ (la & 7)) << 4);
    const int loff1 = la * 128 + (((4 + lg) ^ (la & 7)) << 4);

    f32x4 acc[4][4] = {};
    const int nt = K >> 6;

#pragma unroll
    for (int i = 0; i < 4; ++i) STA_(i, smem, 0);
#pragma unroll
    for (int i = 0; i < 4; ++i) STB_(i, smem, 0);
    __builtin_amdgcn_sched_barrier(0);
    asm volatile("s_waitcnt vmcnt(0)" ::: "memory");
    pin_barrier();

    for (int t = 0; t < nt; ++t) {
        char* rq = smem + (t & 1) * 32768;
        char* sq = smem + ((t & 1) ^ 1) * 32768;
        const bool st = (t + 1 < nt);
        const size_t kof = (size_t)(t + 1) * 128;
        const char* aB = rq + wr * 8192;
        const char* bB = rq + 16384 + wc * 8192;

        bf16x8 a0[4], a1[4], b0f[4], b1f[4];
#pragma unroll
        for (int n = 0; n < 4; ++n) b0f[n] = *(const bf16x8*)(bB + n * 2048 + loff0);
#pragma unroll
        for (int m = 0; m < 4; ++m) a0[m] = *(const bf16x8*)(aB + m * 2048 + loff0);
        if (st) { STA_(0, sq, kof); STA_(1, sq, kof); STA_(2, sq, kof); STA_(3, sq, kof); }
#pragma unroll
        for (int n = 0; n < 4; ++n) b1f[n] = *(const bf16x8*)(bB + n * 2048 + loff1);
#pragma unroll
        for (int m = 0; m < 4; ++m) a1[m] = *(const bf16x8*)(aB + m * 2048 + loff1);
        if (st) { STB_(0, sq, kof); STB_(1, sq, kof); STB_(2, sq, kof); STB_(3, sq, kof); }

        __builtin_amdgcn_sched_barrier(0);
        __builtin_amdgcn_s_setprio(1);
#pragma unroll
        for (int m = 0; m < 4; ++m)
#pragma unroll
            for (int n = 0; n < 4; ++n)
                acc[m][n] = MFMA16(a0[m], b0f[n], acc[m][n]);
        __builtin_amdgcn_s_setprio(0);
        __builtin_amdgcn_sched_barrier(0);
        __builtin_amdgcn_s_setprio(1);
#pragma unroll
        for (int m = 0; m < 4; ++m)
#pragma unroll
            for (int n = 0; n < 4; ++n)
                acc[m][n] = MFMA16(a1[m], b1f[n], acc[m][n]);
        __builtin_amdgcn_s_setprio(0);
        __builtin_amdgcn_sched_barrier(0);
        asm volatile("s_waitcnt vmcnt(0)" ::: "memory");
        pin_barrier();
    }
#undef STA_
#undef STB_

    {
        float* cst = (float*)smem;
        const int g4 = lg << 2;
#pragma unroll
        for (int n = 0; n < 4; ++n) {
            int col = wc * 64 + n * 16 + la;
            float bs = bias0[col0 + col] + bias1[col0 + col] + bias2[col0 + col];
#pragma unroll
            for (int m = 0; m < 4; ++m) {
#pragma unroll
                for (int r = 0; r < 4; ++r) {
                    int row = wr * 64 + m * 16 + g4 + r;
                    int scol = col ^ (((row >> 2) & 3) << 3);
                    cst[row * 128 + scol] = acc[m][n][r] + bs;
                }
            }
        }
        pin_barrier();
#pragma unroll
        for (int it = 0; it < 16; ++it) {
            int id = it * 256 + tid;       // 16B chunk: row*32 + c16
            int row = id >> 5, c16 = id & 31;
            int sc16 = c16 ^ (((row >> 2) & 3) << 1);
            u16x8 v = *(const u16x8*)((char*)cst + row * 512 + sc16 * 16);
            *(u16x8*)((char*)C + ((size_t)(row0 + row) * ldc + col0) * 4 + c16 * 16) = v;
        }
    }
}

// ---------------- attention: HP heads per block + XCD-chunked swizzle -------
template <int S, int HP>
__global__ __launch_bounds__(256) void k_attn(const u16* __restrict__ qkv,
                                              u16* __restrict__ ab, int layer) {
    constexpr int NCT = S / 16;
    constexpr int RPW = (S == 32) ? 1 : S / 64;
    constexpr int ACTIVE = (S == 32) ? 2 : 4;
    constexpr int KST = S / 32;
    constexpr int VSTRIDE = 2 * S;
    constexpr int VMASK = VSTRIDE / 16 - 1;
    constexpr int HPB = 16 / HP;               // head-groups per (b,n)

    __shared__ __align__(16) char KS[HP][S * 128];
    __shared__ __align__(16) char VTS[HP][64 * VSTRIDE];
    __shared__ __align__(16) char PS[HP][S * VSTRIDE];

    const int nwg = gridDim.x, bid = blockIdx.x;
    const int cpx = nwg >> 3;
    const int swz = (bid & 7) * cpx + (bid >> 3);

    const int per_b = (4096 / S) * HPB;
    const int b = swz / per_b;
    const int r0 = swz % per_b;
    const int n = r0 / HPB, hbase = (r0 % HPB) * HP;
    const int token0 = b * 4096 + n * S;
    const int tid = threadIdx.x, lane = tid & 63, wave = tid >> 6;
    const int hp = (HP == 2) ? (wave >> 1) : 0;         // this wave's head
    const int lw = (HP == 2) ? (wave & 1) : wave;       // local wave in head

    constexpr int CHUNKS = S / 32;
#pragma unroll
    for (int hs = 0; hs < HP; ++hs) {
        const int colQ = layer * 3072 + (hbase + hs) * 64;
#pragma unroll
        for (int c = 0; c < CHUNKS; ++c) {
            int lc = c * 256 + tid;
            int row = lc >> 3, off = (lc & 7) * 16;
            const char* base = (const char*)qkv + ((size_t)(token0 + row) * 9216 + colQ) * 2 + off;
            u16x8 kv = *(const u16x8*)(base + 1024 * 2);
            *(u16x8*)(KS[hs] + row * 128 + (off ^ ((row & 7) << 4))) = kv;
            u16x8 vv = *(const u16x8*)(base + 2048 * 2);
            int cb = off >> 1;
#pragma unroll
            for (int e = 0; e < 8; ++e) {
                int col = cb + e;
                *(u16*)(VTS[hs] + col * VSTRIDE + ((row * 2) ^ ((col & VMASK) << 4))) = vv[e];
            }
        }
    }
    __syncthreads();

    const int colQ = layer * 3072 + (hbase + hp) * 64;
    f32x4 sacc[RPW][NCT] = {};
    if (lw < ACTIVE) {
#pragma unroll
        for (int rl = 0; rl < RPW; ++rl) {
            int rt = lw * RPW + rl;
#pragma unroll
            for (int ks2 = 0; ks2 < 2; ++ks2) {
                int qrow = token0 + rt * 16 + (lane & 15);
                int kbyte = ks2 * 64 + ((lane >> 4) << 4);
                bf16x8 aq = *(const bf16x8*)((const char*)qkv +
                              ((size_t)qrow * 9216 + colQ) * 2 + kbyte);
#pragma unroll
                for (int ct = 0; ct < NCT; ++ct) {
                    int krow = ct * 16 + (lane & 15);
                    bf16x8 bk = *(const bf16x8*)(KS[hp] + krow * 128 + (kbyte ^ ((krow & 7) << 4)));
                    sacc[rl][ct] = MFMA16(aq, bk, sacc[rl][ct]);
                }
            }
        }
#pragma unroll
        for (int rl = 0; rl < RPW; ++rl) {
            int rt = lw * RPW + rl;
#pragma unroll
            for (int r = 0; r < 4; ++r) {
                float vals[NCT];
                float m = -1e30f;
#pragma unroll
                for (int ct = 0; ct < NCT; ++ct) {
                    vals[ct] = sacc[rl][ct][r] * 0.125f;
                    m = fmaxf(m, vals[ct]);
                }
#pragma unroll
                for (int d = 1; d < 16; d <<= 1) m = fmaxf(m, __shfl_xor(m, d, 64));
                float sum = 0.f;
#pragma unroll
                for (int ct = 0; ct < NCT; ++ct) {
                    float p = exp2f((vals[ct] - m) * 1.44269504f);
                    vals[ct] = p;
                    sum += p;
                }
#pragma unroll
                for (int d = 1; d < 16; d <<= 1) sum += __shfl_xor(sum, d, 64);
                float inv = 1.0f / sum;
                int row = rt * 16 + ((lane >> 4) << 2) + r;
#pragma unroll
                for (int ct = 0; ct < NCT; ++ct) {
                    int col = ct * 16 + (lane & 15);
                    *(u16*)(PS[hp] + row * VSTRIDE + ((col * 2) ^ ((row & VMASK) << 4))) =
                        f2bf(vals[ct] * inv);
                }
            }
        }
    }
    __syncthreads();

    if (lw < ACTIVE) {
        const int colA = layer * 1024 + (hbase + hp) * 64;
#pragma unroll
        for (int rl = 0; rl < RPW; ++rl) {
            int rt = lw * RPW + rl;
            f32x4 oacc[4] = {};
#pragma unroll
            for (int ks2 = 0; ks2 < KST; ++ks2) {
                int kbyte = ks2 * 64 + ((lane >> 4) << 4);
                int prow = rt * 16 + (lane & 15);
                bf16x8 ap = *(const bf16x8*)(PS[hp] + prow * VSTRIDE + (kbyte ^ ((prow & VMASK) << 4)));
#pragma unroll
                for (int ct = 0; ct < 4; ++ct) {
                    int vcol = ct * 16 + (lane & 15);
                    bf16x8 bv = *(const bf16x8*)(VTS[hp] + vcol * VSTRIDE + (kbyte ^ ((vcol & VMASK) << 4)));
                    oacc[ct] = MFMA16(ap, bv, oacc[ct]);
                }
            }
#pragma unroll
            for (int ct = 0; ct < 4; ++ct) {
#pragma unroll
                for (int r = 0; r < 4; ++r) {
                    int row = token0 + rt * 16 + ((lane >> 4) << 2) + r;
                    int col = colA + ct * 16 + (lane & 15);
                    ab[(size_t)row * 3072 + col] = f2bf(oacc[ct][r]);
                }
            }
        }
    }
}

// ---------------------------------------------------------------------------
extern "C" void kernel_launch(void* const* d_in, const int* in_sizes, int n_in,
                              void* d_out, int out_size, void* d_ws, size_t ws_size,
                              hipStream_t stream) {
    const float* x    = (const float*)d_in[0];
    const float* Wqkv = (const float*)d_in[1];
    const float* bqkv = (const float*)d_in[2];
    const float* Wo   = (const float*)d_in[3];
    const float* bo   = (const float*)d_in[4];

    char* ws = (char*)d_ws;
    u16* XE    = (u16*)(ws);                       // [8192][1024]
    u16* WQKVT = (u16*)(ws + 16777216);            // [9216][1024]
    u16* WOT   = (u16*)(ws + 35651584);            // [1024][3072]
    u16* QKVB  = (u16*)(ws + 41943040);            // [8192][9216]
    u16* ABUF  = (u16*)(ws + 192937984);           // [8192][3072]

    k_prep_xe<<<8192, 256, 0, stream>>>(x, XE);
    k_transpose_both<<<3072, 256, 0, stream>>>(Wqkv, WQKVT, Wo, WOT);

    // QKV projection for all 3 layers: [8192,1024] @ [1024,9216]
    // grid 1152 = 8 XCD x (4 bx x 36 by); gxl = 4
    k_gemm4<256, true><<<dim3(1152), 512, 0, stream>>>(
        XE, WQKVT, QKVB, bqkv, nullptr, nullptr, 1024, 1024, 1024, 9216, 4);

    // dilated segment attention per layer (S=32 packs 2 heads/block)
    k_attn<32, 2><<<2048, 256, 0, stream>>>(QKVB, ABUF, 0);
    k_attn<64, 1><<<2048, 256, 0, stream>>>(QKVB, ABUF, 1);
    k_attn<128, 1><<<1024, 256, 0, stream>>>(QKVB, ABUF, 2);

    // fused output projection + layer sum: [8192,3072] @ [3072,1024]
    // grid 512 = 8 XCD x (8 bx x 8 by); gxl = 8 (A-resident mapping)
    k_gemm4b<<<dim3(512), 256, 0, stream>>>(
        ABUF, WOT, (float*)d_out, bo, bo + 1024, bo + 2048,
        3072, 3072, 3072, 1024, 8);
}